// Round 1
// baseline (165.124 us; speedup 1.0000x reference)
//
#include <hip/hip_runtime.h>
#include <stdint.h>

// Problem constants (B,H,W,C) = (8,128,128,64); out width = (W-1)+H = 255.
#define BB 8
#define HH 128
#define WW 128
#define CC 64
#define OUTW 255

// X staging: 128 rows of bf16, padded 64 -> 72 elems (144 B): keeps 16B
// alignment for ds_read_b128 and offsets consecutive rows by 4 banks.
#define LDS_STRIDE 72
// Epilogue staging: 8 G-rows x 132 floats per wave, carved out of the SAME
// LDS buffer as xs after the MFMA phase (union). 132: 2*132 mod 32 == 8 so
// the quad-strided scatter lands 2 lanes/bank (free, m136).
#define EP_STRIDE 132

typedef __attribute__((ext_vector_type(8))) short bf16x8;   // 8 bf16 in 4 VGPRs
typedef __attribute__((ext_vector_type(4))) float f32x4;

__device__ __forceinline__ unsigned short f2bf(float f) {
    union { float f; uint32_t u; } v; v.f = f;
    uint32_t u = v.u;
    // round-to-nearest-even; inputs are finite normals
    return (unsigned short)((u + 0x7FFFu + ((u >> 16) & 1u)) >> 16);
}

// One block computes one 128x128 Gram matrix G = X * X^T, X = 128x64.
// Block mapping INTERLEAVES row- and col-gram blocks (g&1) so that all 256
// writers of one batch image's 16.7 MB output region are dispatched in one
// temporal window -> junction cache lines and DRAM pages of out[b,i,:,:] get
// written close in time (L2 merge, DRAM page locality).
//
// LDS is a UNION: xs (18432 B) during stage+MFMA, then reused as 4 wave-
// private ep strips (4 x 8 x 132 x 4 = 16896 B) for the store-staging
// epilogue. Total LDS 18432 B -> no longer the occupancy limiter (was
// 51712 B = 3 blocks/CU; now VGPR-bound, >=4 blocks/CU).
__global__ __launch_bounds__(256, 4)
void criss_cross_gram_kernel(const float* __restrict__ x, float* __restrict__ out) {
    __shared__ __align__(16) unsigned char smem[128 * LDS_STRIDE * 2];  // 18432 B
    unsigned short* xs = (unsigned short*)smem;

    const int g = blockIdx.x;          // grid = 2048 = 8 * 256
    const int b = g >> 8;
    const int rem = g & 255;
    const bool isCol = (rem & 1);
    const int p = rem >> 1;            // i (row gram) or j (col gram)

    const float* xbase;
    int xRowStride;      // floats between consecutive X rows
    int outBase;         // float offset of G-row 0 in out
    int outRowStride;    // floats between consecutive G rows in out
    if (!isCol) {
        xbase        = x + ((b * HH + p) * WW) * CC;   // x[b,p,0,:]
        xRowStride   = CC;                              // row pixels contiguous
        outBase      = ((b * HH + p) * WW) * OUTW;      // out[b,p,j,*]
        outRowStride = OUTW;
    } else {
        xbase        = x + (b * HH * WW + p) * CC;      // x[b,0,p,:]
        xRowStride   = WW * CC;                         // column pixels strided
        outBase      = (b * HH * WW + p) * OUTW;        // out[b,i,p,127+*]
        outRowStride = WW * OUTW;
    }

    const int t = threadIdx.x;
    const int wave = t >> 6;
    const int lane = t & 63;
    const int m16  = lane & 15;
    const int quad = lane >> 4;

    // ---- Stage X (128x64 fp32) into LDS as bf16. 2048 float4 loads total.
    // Batched: issue ALL 8 loads first (one memory-latency exposure instead
    // of 8 serialized load->convert->write round-trips through L3).
    float4 v[8];
    #pragma unroll
    for (int r = 0; r < 8; ++r) {
        const int idx = r * 256 + t;        // 0..2047
        const int row = idx >> 4;           // 0..127
        const int c4  = (idx & 15) << 2;    // float4 column
        v[r] = *(const float4*)(xbase + row * xRowStride + c4);
    }

    // acc init in the shadow of the loads
    f32x4 acc[2][8];
    #pragma unroll
    for (int rt = 0; rt < 2; ++rt)
        #pragma unroll
        for (int ct = 0; ct < 8; ++ct)
            acc[rt][ct] = (f32x4){0.f, 0.f, 0.f, 0.f};

    #pragma unroll
    for (int r = 0; r < 8; ++r) {
        const int idx = r * 256 + t;
        const int row = idx >> 4;
        const int c4  = (idx & 15) << 2;
        ushort4* dst = (ushort4*)&xs[row * LDS_STRIDE + c4];
        *dst = make_ushort4(f2bf(v[r].x), f2bf(v[r].y), f2bf(v[r].z), f2bf(v[r].w));
    }
    __syncthreads();

    // ---- MFMA: wave w computes G rows [w*32, w*32+32) x all 128 cols. ----
    #pragma unroll
    for (int ks = 0; ks < 2; ++ks) {
        const int kOff = ks * 32 + quad * 8;
        bf16x8 afrag[2];
        #pragma unroll
        for (int rt = 0; rt < 2; ++rt) {
            const int row = wave * 32 + rt * 16 + m16;
            afrag[rt] = *(const bf16x8*)&xs[row * LDS_STRIDE + kOff];
        }
        #pragma unroll
        for (int ct = 0; ct < 8; ++ct) {
            const int row = ct * 16 + m16;
            const bf16x8 bfrag = *(const bf16x8*)&xs[row * LDS_STRIDE + kOff];
            acc[0][ct] = __builtin_amdgcn_mfma_f32_16x16x32_bf16(afrag[0], bfrag, acc[0][ct], 0, 0, 0);
            acc[1][ct] = __builtin_amdgcn_mfma_f32_16x16x32_bf16(afrag[1], bfrag, acc[1][ct], 0, 0, 0);
        }
    }

    // All waves are done READING xs before anyone overwrites it with ep data.
    __syncthreads();

    // ---- Epilogue: wave-private LDS round-trip, then contiguous 256B stores.
    // Chunked to 8 G-rows per pass so 4 waves fit in the xs footprint.
    // Chunk c covers accumulator regs {2c, 2c+1} of every quad: all 64 lanes
    // stay active in the scatter. slot = quad*2 + (reg&1); global row =
    // rowBase + quad*4 + 2c + (reg&1).
    // Same-wave ds ordering (in-order LDS pipe + lgkmcnt) makes the
    // write->read and read->next-chunk-write dependencies safe, no barrier.
    // C/D layout: col = lane&15, row = quad*4 + reg.
    float* myep = (float*)smem + wave * (8 * EP_STRIDE);

    #pragma unroll
    for (int rt = 0; rt < 2; ++rt) {
        const int rowBase = wave * 32 + rt * 16;

        #pragma unroll
        for (int c = 0; c < 2; ++c) {
            // Scatter C fragments into LDS, applying diagonal compaction here
            // (cheap LDS predication instead of predicated global stores).
            #pragma unroll
            for (int ct = 0; ct < 8; ++ct) {
                #pragma unroll
                for (int rr = 0; rr < 2; ++rr) {
                    const int reg  = 2 * c + rr;
                    const int slot = quad * 2 + rr;     // 0..7
                    const int gm   = rowBase + quad * 4 + reg;
                    const int gn   = ct * 16 + m16;
                    const float val = acc[rt][ct][reg];
                    if (isCol) {
                        myep[slot * EP_STRIDE + gn] = val;
                    } else if (gn != gm) {
                        myep[slot * EP_STRIDE + (gn - (gn > gm ? 1 : 0))] = val;
                    }
                }
            }

            // Linear read-back + contiguous global stores: 2 x 256B per G-row.
            #pragma unroll
            for (int s = 0; s < 8; ++s) {
                const int grow = rowBase + (s >> 1) * 4 + 2 * c + (s & 1);
                float* rp = out + outBase + grow * outRowStride + (isCol ? 127 : 0);
                rp[lane] = myep[s * EP_STRIDE + lane];
                if (isCol || lane < 63)   // col: 64 floats, row: 63 floats in 2nd half
                    rp[64 + lane] = myep[s * EP_STRIDE + 64 + lane];
            }
        }
    }
}

extern "C" void kernel_launch(void* const* d_in, const int* in_sizes, int n_in,
                              void* d_out, int out_size, void* d_ws, size_t ws_size,
                              hipStream_t stream) {
    const float* x = (const float*)d_in[0];
    float* out = (float*)d_out;
    // 2048 blocks: interleaved row/col gram writers, one 128x128 Gram each.
    criss_cross_gram_kernel<<<dim3(BB * (HH + WW)), dim3(256), 0, stream>>>(x, out);
}